// Round 2
// baseline (6769.333 us; speedup 1.0000x reference)
//
#include <hip/hip_runtime.h>
#include <hip/hip_bf16.h>

#define HD 128
#define ED 16
#define TD 32

typedef __attribute__((ext_vector_type(8))) short short8;
typedef __attribute__((ext_vector_type(4))) float float4v;

__device__ __forceinline__ float siluf(float v){ return v * (1.0f / (1.0f + __expf(-v))); }

// bf16 pack/unpack helpers (RTNE)
__device__ __forceinline__ unsigned int bfbits(float x){
  unsigned int a = __float_as_uint(x);
  return (a + 0x7fffu + ((a >> 16) & 1u)) >> 16;
}
__device__ __forceinline__ unsigned int packbf(float lo, float hi){
  return (bfbits(lo) & 0xffffu) | (bfbits(hi) << 16);
}
__device__ __forceinline__ float unplo(unsigned int w){ return __uint_as_float(w << 16); }
__device__ __forceinline__ float unphi(unsigned int w){ return __uint_as_float(w & 0xffff0000u); }
__device__ __forceinline__ float b2f(unsigned short s){ return __uint_as_float(((unsigned int)s) << 16); }
__device__ __forceinline__ unsigned short f2b(float x){ return (unsigned short)bfbits(x); }

__device__ __forceinline__ void unp8(uint4 u, float* f){
  f[0]=unplo(u.x); f[1]=unphi(u.x); f[2]=unplo(u.y); f[3]=unphi(u.y);
  f[4]=unplo(u.z); f[5]=unphi(u.z); f[6]=unplo(u.w); f[7]=unphi(u.w);
}

__device__ __forceinline__ void atomAddF(float* p, float v){
  unsafeAtomicAdd(p, v);  // HW global_atomic_add_f32 on gfx950
}

// ---------------------------------------------------------------------------
// Kernel 1: per-node first-layer tables (unchanged from R1 — fast).
//  Aes = h @ We_w1[0:128] + t @ We_w1[273:305] + We_b1
//  Aed = h @ We_w1[128:256]
//  Axs = h @ Wx_w1[0:128] + t @ Wx_w1[272:304] + Wx_b1
//  Axd = h @ Wx_w1[128:256]
// ---------------------------------------------------------------------------
__global__ void __launch_bounds__(256) k_pre(
    const float* __restrict__ h, const float* __restrict__ t_emb,
    const float* __restrict__ We_w1, const float* __restrict__ We_b1,
    const float* __restrict__ Wx_w1, const float* __restrict__ Wx_b1,
    unsigned short* __restrict__ Aes, unsigned short* __restrict__ Aed,
    unsigned short* __restrict__ Axs, unsigned short* __restrict__ Axd,
    int N)
{
  const int table = blockIdx.y;
  const bool isE   = (table <= 1);
  const bool isSrc = (table == 0 || table == 2);
  const float* W    = isE ? We_w1 : Wx_w1;
  const float* bias = (table == 0) ? We_b1 : (table == 2 ? Wx_b1 : nullptr);
  unsigned short* out = (table == 0) ? Aes : (table == 1) ? Aed : (table == 2) ? Axs : Axd;
  const int K = isSrc ? (HD + TD) : HD;
  const int tRowBase = isE ? 273 : 272;

  __shared__ unsigned int Wp[(HD + TD) * 64];

  for (int i = threadIdx.x; i < K * 64; i += 256){
    int k = i >> 6, l = i & 63;
    int row = (k < HD) ? (isSrc ? k : (HD + k)) : (tRowBase + (k - HD));
    Wp[i] = packbf(W[row * HD + l], W[row * HD + l + 64]);
  }
  __syncthreads();

  const int lane = threadIdx.x & 63, wave = threadIdx.x >> 6;
  const int nw = gridDim.x * 4;
  const float bb0 = bias ? bias[lane]      : 0.f;
  const float bb1 = bias ? bias[lane + 64] : 0.f;

  for (int n = blockIdx.x * 4 + wave; n < N; n += nw){
    float f0 = h[(size_t)n * HD + lane];
    float f1 = h[(size_t)n * HD + 64 + lane];
    float f2 = (isSrc && lane < TD) ? t_emb[(size_t)n * TD + lane] : 0.f;
    float a0 = bb0, a1 = bb1;
    #pragma unroll
    for (int k = 0; k < 64; ++k){
      float fk = __shfl(f0, k);
      unsigned int w = Wp[k * 64 + lane];
      a0 = fmaf(fk, unplo(w), a0); a1 = fmaf(fk, unphi(w), a1);
    }
    #pragma unroll
    for (int k = 0; k < 64; ++k){
      float fk = __shfl(f1, k);
      unsigned int w = Wp[(64 + k) * 64 + lane];
      a0 = fmaf(fk, unplo(w), a0); a1 = fmaf(fk, unphi(w), a1);
    }
    if (isSrc){
      #pragma unroll
      for (int k = 0; k < TD; ++k){
        float fk = __shfl(f2, k);
        unsigned int w = Wp[(HD + k) * 64 + lane];
        a0 = fmaf(fk, unplo(w), a0); a1 = fmaf(fk, unphi(w), a1);
      }
    }
    out[(size_t)n * HD + lane]      = f2b(a0);
    out[(size_t)n * HD + 64 + lane] = f2b(a1);
  }
}

// ---------------------------------------------------------------------------
// Kernel 2: fused MFMA edge kernel. One wave = 16 edges.
// A-frag (16x16x32 bf16): lane l -> edge m = l&15, k = (l>>4)*8 + j (+32*step)
// C-frag: col n = l&15, row(edge) = (l>>4)*4 + reg   [m89/m91 verified layout]
// B staged transposed in LDS: W2t[n][k] bf16, row stride 136 ushorts (pad -> b128 floor)
// ---------------------------------------------------------------------------
#define W2S 136

__global__ void __launch_bounds__(256) k_edge(
    const int* __restrict__ ei, const float* __restrict__ x,
    const float* __restrict__ ea,
    const unsigned short* __restrict__ Aes, const unsigned short* __restrict__ Aed,
    const unsigned short* __restrict__ Axs, const unsigned short* __restrict__ Axd,
    const float* __restrict__ We_w1, const float* __restrict__ We_w2,
    const float* __restrict__ We_b2, const float* __restrict__ Watt_w,
    const float* __restrict__ Watt_b,
    const float* __restrict__ Wx_w1, const float* __restrict__ Wx_w2,
    const float* __restrict__ Wx_b2, const float* __restrict__ Wx_w3,
    float* __restrict__ msg_agg, float* __restrict__ xout, int E)
{
  __shared__ unsigned short W2tE[128 * W2S];   // 34,816 B
  __shared__ unsigned short W2tX[128 * W2S];   // 34,816 B
  __shared__ unsigned short W1dE[17 * 128];    // rows 0..15 = We rows 257..272 (ea), row 16 = We row 256 (dist)
  __shared__ unsigned short W1dX[17 * 128];    // rows 0..15 = Wx rows 256..271 (ea), row 16 = 0

  for (int i = threadIdx.x; i < 128 * 128; i += 256){
    int n = i & 127, k = i >> 7;
    W2tE[n * W2S + k] = f2b(We_w2[k * 128 + n]);
    W2tX[n * W2S + k] = f2b(Wx_w2[k * 128 + n]);
  }
  for (int i = threadIdx.x; i < 17 * 128; i += 256){
    int j2 = i >> 7, n = i & 127;
    W1dE[i] = f2b(j2 < 16 ? We_w1[(257 + j2) * 128 + n] : We_w1[256 * 128 + n]);
    W1dX[i] = f2b(j2 < 16 ? Wx_w1[(256 + j2) * 128 + n] : 0.f);
  }
  __syncthreads();

  const int lane = threadIdx.x & 63, wave = threadIdx.x >> 6;
  const int m = lane & 15;          // edge-in-tile (A) / col-in-tile (B,C)
  const int q = lane >> 4;          // k-chunk (A,B) / row-group (C)

  // per-lane epilogue constants (col = t*16 + m)
  float web2[8], watt[8], wxb2[8], w3v[8];
  #pragma unroll
  for (int t = 0; t < 8; ++t){
    web2[t] = We_b2[t * 16 + m];
    watt[t] = Watt_w[t * 16 + m];
    wxb2[t] = Wx_b2[t * 16 + m];
    w3v[t]  = Wx_w3[t * 16 + m];
  }
  const float attb = Watt_b[0];

  const int tiles = (E + 15) >> 4;
  const int nw = gridDim.x * 4;

  for (int tb = blockIdx.x * 4 + wave; tb < tiles; tb += nw){
    const int e0 = tb << 4;
    const int e  = e0 + m;
    const int eC = e < E ? e : (E - 1);
    const int s = ei[eC], d = ei[E + eC];

    float dx = x[s * 3 + 0] - x[d * 3 + 0];
    float dy = x[s * 3 + 1] - x[d * 3 + 1];
    float dz = x[s * 3 + 2] - x[d * 3 + 2];
    float dist = dx * dx + dy * dy + dz * dz;
    float rs = 2.5f / (sqrtf(dist + 1e-8f) + 1.0f);
    const float4 eav = *(const float4*)(ea + (size_t)eC * ED + q * 4);

    float4v accE[8], accX[8];
    #pragma unroll
    for (int t = 0; t < 8; ++t){
      accE[t] = (float4v){0.f, 0.f, 0.f, 0.f};
      accX[t] = (float4v){0.f, 0.f, 0.f, 0.f};
    }

    #pragma unroll
    for (int step = 0; step < 4; ++step){
      const int kb = step * 32 + q * 8;
      uint4 ges = *(const uint4*)(Aes + (size_t)s * HD + kb);
      uint4 ged = *(const uint4*)(Aed + (size_t)d * HD + kb);
      uint4 gxs = *(const uint4*)(Axs + (size_t)s * HD + kb);
      uint4 gxd = *(const uint4*)(Axd + (size_t)d * HD + kb);
      float fa[8], fb[8], pe[8], px[8];
      unp8(ges, fa); unp8(ged, fb);
      #pragma unroll
      for (int j = 0; j < 8; ++j) pe[j] = fa[j] + fb[j];
      unp8(gxs, fa); unp8(gxd, fb);
      #pragma unroll
      for (int j = 0; j < 8; ++j) px[j] = fa[j] + fb[j];

      // ea + dist first-layer term (k = 0..16 of the tail block)
      #pragma unroll
      for (int j2 = 0; j2 < 17; ++j2){
        float eaj;
        if (j2 < 16){
          float comp = ((j2 & 3) == 0) ? eav.x : ((j2 & 3) == 1) ? eav.y
                     : ((j2 & 3) == 2) ? eav.z : eav.w;
          eaj = __shfl(comp, ((j2 >> 2) << 4) | m);
        } else {
          eaj = dist;   // own edge's dist_sq (k==16 row: We row 256 / zeros for X)
        }
        uint4 wE = *(const uint4*)(W1dE + j2 * 128 + kb);
        uint4 wX = *(const uint4*)(W1dX + j2 * 128 + kb);
        float fE[8], fX[8];
        unp8(wE, fE); unp8(wX, fX);
        #pragma unroll
        for (int j = 0; j < 8; ++j){
          pe[j] = fmaf(eaj, fE[j], pe[j]);
          px[j] = fmaf(eaj, fX[j], px[j]);
        }
      }

      // silu -> bf16 A-frags
      union { short8 v; unsigned int u[4]; } ae, ax;
      #pragma unroll
      for (int jj = 0; jj < 4; ++jj){
        ae.u[jj] = packbf(siluf(pe[2 * jj]), siluf(pe[2 * jj + 1]));
        ax.u[jj] = packbf(siluf(px[2 * jj]), siluf(px[2 * jj + 1]));
      }

      // layer-2 MFMAs over 8 n-tiles
      #pragma unroll
      for (int t = 0; t < 8; ++t){
        short8 bE = *(const short8*)(W2tE + (size_t)(t * 16 + m) * W2S + kb);
        short8 bX = *(const short8*)(W2tX + (size_t)(t * 16 + m) * W2S + kb);
        accE[t] = __builtin_amdgcn_mfma_f32_16x16x32_bf16(ae.v, bE, accE[t], 0, 0, 0);
        accX[t] = __builtin_amdgcn_mfma_f32_16x16x32_bf16(ax.v, bX, accX[t], 0, 0, 0);
      }
    }

    // ---- epilogue: lane holds D[edge=(q*4+r)][n=t*16+m] in acc*[t][r] ----
    // attention dot + sigmoid
    float attp[4] = {0.f, 0.f, 0.f, 0.f};
    #pragma unroll
    for (int t = 0; t < 8; ++t)
      #pragma unroll
      for (int r = 0; r < 4; ++r)
        attp[r] = fmaf(accE[t][r] + web2[t], watt[t], attp[r]);
    #pragma unroll
    for (int r = 0; r < 4; ++r){
      attp[r] += __shfl_xor(attp[r], 1);
      attp[r] += __shfl_xor(attp[r], 2);
      attp[r] += __shfl_xor(attp[r], 4);
      attp[r] += __shfl_xor(attp[r], 8);
    }
    float att[4];
    #pragma unroll
    for (int r = 0; r < 4; ++r)
      att[r] = 1.f / (1.f + __expf(-(attp[r] + attb)));

    int dd[4], ee[4];
    #pragma unroll
    for (int r = 0; r < 4; ++r){
      dd[r] = __shfl(d, q * 4 + r);
      ee[r] = e0 + q * 4 + r;
    }

    #pragma unroll
    for (int r = 0; r < 4; ++r){
      if (ee[r] < E){
        #pragma unroll
        for (int t = 0; t < 8; ++t)
          atomAddF(msg_agg + (size_t)dd[r] * HD + t * 16 + m,
                   att[r] * (accE[t][r] + web2[t]));
      }
    }

    // coord weight: silu(layer2) . w3 -> tanh -> scatter
    float cwp[4] = {0.f, 0.f, 0.f, 0.f};
    #pragma unroll
    for (int t = 0; t < 8; ++t)
      #pragma unroll
      for (int r = 0; r < 4; ++r)
        cwp[r] = fmaf(siluf(accX[t][r] + wxb2[t]), w3v[t], cwp[r]);
    #pragma unroll
    for (int r = 0; r < 4; ++r){
      cwp[r] += __shfl_xor(cwp[r], 1);
      cwp[r] += __shfl_xor(cwp[r], 2);
      cwp[r] += __shfl_xor(cwp[r], 4);
      cwp[r] += __shfl_xor(cwp[r], 8);
    }
    float scv[4];
    #pragma unroll
    for (int r = 0; r < 4; ++r)
      scv[r] = tanhf(cwp[r]) * __shfl(rs, q * 4 + r);

    // lanes m<4 of each 16-lane group scatter edge r=m's 3 components
    const int rr = m & 3;
    float dxe = __shfl(dx, q * 4 + rr);
    float dye = __shfl(dy, q * 4 + rr);
    float dze = __shfl(dz, q * 4 + rr);
    float scc = (rr == 0) ? scv[0] : (rr == 1) ? scv[1] : (rr == 2) ? scv[2] : scv[3];
    int   ddc = (rr == 0) ? dd[0]  : (rr == 1) ? dd[1]  : (rr == 2) ? dd[2]  : dd[3];
    int   eec = (rr == 0) ? ee[0]  : (rr == 1) ? ee[1]  : (rr == 2) ? ee[2]  : ee[3];
    if (m < 4 && eec < E){
      atomAddF(xout + (size_t)ddc * 3 + 0, dxe * scc);
      atomAddF(xout + (size_t)ddc * 3 + 1, dye * scc);
      atomAddF(xout + (size_t)ddc * 3 + 2, dze * scc);
    }
  }
}

// ---------------------------------------------------------------------------
// Kernel 3a: z = h @ Wh_w1[0:128] + Wh_b1   (fp32, no silu yet)
// ---------------------------------------------------------------------------
__global__ void __launch_bounds__(256) k_h1a(
    const float* __restrict__ h, const float* __restrict__ Wh_w1,
    const float* __restrict__ Wh_b1, float* __restrict__ z, int N)
{
  __shared__ unsigned int Wp[HD * 64];
  for (int i = threadIdx.x; i < HD * 64; i += 256){
    int k = i >> 6, l = i & 63;
    Wp[i] = packbf(Wh_w1[k * HD + l], Wh_w1[k * HD + l + 64]);
  }
  __syncthreads();

  const int lane = threadIdx.x & 63, wave = threadIdx.x >> 6;
  const int nw = gridDim.x * 4;
  const float bb0 = Wh_b1[lane], bb1 = Wh_b1[lane + 64];

  for (int n = blockIdx.x * 4 + wave; n < N; n += nw){
    float f0 = h[(size_t)n * HD + lane];
    float f1 = h[(size_t)n * HD + 64 + lane];
    float a0 = bb0, a1 = bb1;
    #pragma unroll
    for (int k = 0; k < 64; ++k){
      float fk = __shfl(f0, k);
      unsigned int w = Wp[k * 64 + lane];
      a0 = fmaf(fk, unplo(w), a0); a1 = fmaf(fk, unphi(w), a1);
    }
    #pragma unroll
    for (int k = 0; k < 64; ++k){
      float fk = __shfl(f1, k);
      unsigned int w = Wp[(64 + k) * 64 + lane];
      a0 = fmaf(fk, unplo(w), a0); a1 = fmaf(fk, unphi(w), a1);
    }
    z[(size_t)n * HD + lane]      = a0;
    z[(size_t)n * HD + 64 + lane] = a1;
  }
}

// ---------------------------------------------------------------------------
// Kernel 3b: z = silu(z + msg @ Wh_w1[128:256])
// ---------------------------------------------------------------------------
__global__ void __launch_bounds__(256) k_h1b(
    const float* __restrict__ msg, const float* __restrict__ Wh_w1,
    float* __restrict__ z, int N)
{
  __shared__ unsigned int Wp[HD * 64];
  for (int i = threadIdx.x; i < HD * 64; i += 256){
    int k = i >> 6, l = i & 63;
    Wp[i] = packbf(Wh_w1[(HD + k) * HD + l], Wh_w1[(HD + k) * HD + l + 64]);
  }
  __syncthreads();

  const int lane = threadIdx.x & 63, wave = threadIdx.x >> 6;
  const int nw = gridDim.x * 4;

  for (int n = blockIdx.x * 4 + wave; n < N; n += nw){
    float f0 = msg[(size_t)n * HD + lane];
    float f1 = msg[(size_t)n * HD + 64 + lane];
    float a0 = z[(size_t)n * HD + lane];
    float a1 = z[(size_t)n * HD + 64 + lane];
    #pragma unroll
    for (int k = 0; k < 64; ++k){
      float fk = __shfl(f0, k);
      unsigned int w = Wp[k * 64 + lane];
      a0 = fmaf(fk, unplo(w), a0); a1 = fmaf(fk, unphi(w), a1);
    }
    #pragma unroll
    for (int k = 0; k < 64; ++k){
      float fk = __shfl(f1, k);
      unsigned int w = Wp[(64 + k) * 64 + lane];
      a0 = fmaf(fk, unplo(w), a0); a1 = fmaf(fk, unphi(w), a1);
    }
    z[(size_t)n * HD + lane]      = siluf(a0);
    z[(size_t)n * HD + 64 + lane] = siluf(a1);
  }
}

// ---------------------------------------------------------------------------
// Kernel 4: hout = h + z @ Wh_w2 + Wh_b2
// ---------------------------------------------------------------------------
__global__ void __launch_bounds__(256) k_h2(
    const float* __restrict__ h, const float* __restrict__ z,
    const float* __restrict__ Wh_w2, const float* __restrict__ Wh_b2,
    float* __restrict__ hout, int N)
{
  __shared__ unsigned int Wp[HD * 64];
  for (int i = threadIdx.x; i < HD * 64; i += 256){
    int k = i >> 6, l = i & 63;
    Wp[i] = packbf(Wh_w2[k * HD + l], Wh_w2[k * HD + l + 64]);
  }
  __syncthreads();

  const int lane = threadIdx.x & 63, wave = threadIdx.x >> 6;
  const int nw = gridDim.x * 4;
  const float bb0 = Wh_b2[lane], bb1 = Wh_b2[lane + 64];

  for (int n = blockIdx.x * 4 + wave; n < N; n += nw){
    float f0 = z[(size_t)n * HD + lane];
    float f1 = z[(size_t)n * HD + 64 + lane];
    float a0 = bb0, a1 = bb1;
    #pragma unroll
    for (int k = 0; k < 64; ++k){
      float fk = __shfl(f0, k);
      unsigned int w = Wp[k * 64 + lane];
      a0 = fmaf(fk, unplo(w), a0); a1 = fmaf(fk, unphi(w), a1);
    }
    #pragma unroll
    for (int k = 0; k < 64; ++k){
      float fk = __shfl(f1, k);
      unsigned int w = Wp[(64 + k) * 64 + lane];
      a0 = fmaf(fk, unplo(w), a0); a1 = fmaf(fk, unphi(w), a1);
    }
    hout[(size_t)n * HD + lane]      = h[(size_t)n * HD + lane]      + a0;
    hout[(size_t)n * HD + 64 + lane] = h[(size_t)n * HD + 64 + lane] + a1;
  }
}

extern "C" void kernel_launch(void* const* d_in, const int* in_sizes, int n_in,
                              void* d_out, int out_size, void* d_ws, size_t ws_size,
                              hipStream_t stream)
{
  const float* h      = (const float*)d_in[0];
  const float* x      = (const float*)d_in[1];
  const int*   ei     = (const int*)  d_in[2];
  const float* ea     = (const float*)d_in[3];
  const float* t_emb  = (const float*)d_in[4];
  const float* We_w1  = (const float*)d_in[5];
  const float* We_b1  = (const float*)d_in[6];
  const float* We_w2  = (const float*)d_in[7];
  const float* We_b2  = (const float*)d_in[8];
  const float* Watt_w = (const float*)d_in[9];
  const float* Watt_b = (const float*)d_in[10];
  const float* Wx_w1  = (const float*)d_in[11];
  const float* Wx_b1  = (const float*)d_in[12];
  const float* Wx_w2  = (const float*)d_in[13];
  const float* Wx_b2  = (const float*)d_in[14];
  const float* Wx_w3  = (const float*)d_in[15];
  const float* Wh_w1  = (const float*)d_in[16];
  const float* Wh_b1  = (const float*)d_in[17];
  const float* Wh_w2  = (const float*)d_in[18];
  const float* Wh_b2  = (const float*)d_in[19];

  const int N = in_sizes[0] / HD;
  const int E = in_sizes[2] / 2;

  char* ws = (char*)d_ws;
  unsigned short* Aes = (unsigned short*)ws;  ws += (size_t)N * HD * 2;
  unsigned short* Aed = (unsigned short*)ws;  ws += (size_t)N * HD * 2;
  unsigned short* Axs = (unsigned short*)ws;  ws += (size_t)N * HD * 2;
  unsigned short* Axd = (unsigned short*)ws;  ws += (size_t)N * HD * 2;
  float* msg_agg = (float*)ws;                ws += (size_t)N * HD * 4;
  float* z       = (float*)ws;                ws += (size_t)N * HD * 4;

  float* hout = (float*)d_out;
  float* xout = hout + (size_t)N * HD;

  hipMemsetAsync(msg_agg, 0, (size_t)N * HD * 4, stream);
  hipMemcpyAsync(xout, x, (size_t)N * 3 * 4, hipMemcpyDeviceToDevice, stream);

  dim3 gP(128, 4);
  k_pre<<<gP, 256, 0, stream>>>(h, t_emb, We_w1, We_b1, Wx_w1, Wx_b1,
                                Aes, Aed, Axs, Axd, N);
  k_h1a<<<512, 256, 0, stream>>>(h, Wh_w1, Wh_b1, z, N);
  k_edge<<<512, 256, 0, stream>>>(ei, x, ea, Aes, Aed, Axs, Axd,
                                  We_w1, We_w2, We_b2, Watt_w, Watt_b,
                                  Wx_w1, Wx_w2, Wx_b2, Wx_w3,
                                  msg_agg, xout, E);
  k_h1b<<<512, 256, 0, stream>>>(msg_agg, Wh_w1, z, N);
  k_h2<<<512, 256, 0, stream>>>(h, z, Wh_w2, Wh_b2, hout, N);
}

// Round 3
// 1793.599 us; speedup vs baseline: 3.7742x; 3.7742x over previous
//
#include <hip/hip_runtime.h>
#include <hip/hip_bf16.h>

#define HD 128
#define ED 16
#define TD 32

typedef __attribute__((ext_vector_type(8))) short short8;
typedef __attribute__((ext_vector_type(4))) float float4v;

__device__ __forceinline__ float siluf(float v){ return v * (1.0f / (1.0f + __expf(-v))); }

// bf16 pack/unpack helpers (RTNE)
__device__ __forceinline__ unsigned int bfbits(float x){
  unsigned int a = __float_as_uint(x);
  return (a + 0x7fffu + ((a >> 16) & 1u)) >> 16;
}
__device__ __forceinline__ unsigned int packbf(float lo, float hi){
  return (bfbits(lo) & 0xffffu) | (bfbits(hi) << 16);
}
__device__ __forceinline__ float unplo(unsigned int w){ return __uint_as_float(w << 16); }
__device__ __forceinline__ float unphi(unsigned int w){ return __uint_as_float(w & 0xffff0000u); }
__device__ __forceinline__ float b2f(unsigned short s){ return __uint_as_float(((unsigned int)s) << 16); }
__device__ __forceinline__ unsigned short f2b(float x){ return (unsigned short)bfbits(x); }

__device__ __forceinline__ void unp8(uint4 u, float* f){
  f[0]=unplo(u.x); f[1]=unphi(u.x); f[2]=unplo(u.y); f[3]=unphi(u.y);
  f[4]=unplo(u.z); f[5]=unphi(u.z); f[6]=unplo(u.w); f[7]=unphi(u.w);
}

__device__ __forceinline__ void atomAddF(float* p, float v){
  unsafeAtomicAdd(p, v);  // HW global_atomic_add_f32 on gfx950
}

// ---------------------------------------------------------------------------
// Kernel 1: per-node first-layer tables (unchanged — proven fast).
// ---------------------------------------------------------------------------
__global__ void __launch_bounds__(256) k_pre(
    const float* __restrict__ h, const float* __restrict__ t_emb,
    const float* __restrict__ We_w1, const float* __restrict__ We_b1,
    const float* __restrict__ Wx_w1, const float* __restrict__ Wx_b1,
    unsigned short* __restrict__ Aes, unsigned short* __restrict__ Aed,
    unsigned short* __restrict__ Axs, unsigned short* __restrict__ Axd,
    int N)
{
  const int table = blockIdx.y;
  const bool isE   = (table <= 1);
  const bool isSrc = (table == 0 || table == 2);
  const float* W    = isE ? We_w1 : Wx_w1;
  const float* bias = (table == 0) ? We_b1 : (table == 2 ? Wx_b1 : nullptr);
  unsigned short* out = (table == 0) ? Aes : (table == 1) ? Aed : (table == 2) ? Axs : Axd;
  const int K = isSrc ? (HD + TD) : HD;
  const int tRowBase = isE ? 273 : 272;

  __shared__ unsigned int Wp[(HD + TD) * 64];

  for (int i = threadIdx.x; i < K * 64; i += 256){
    int k = i >> 6, l = i & 63;
    int row = (k < HD) ? (isSrc ? k : (HD + k)) : (tRowBase + (k - HD));
    Wp[i] = packbf(W[row * HD + l], W[row * HD + l + 64]);
  }
  __syncthreads();

  const int lane = threadIdx.x & 63, wave = threadIdx.x >> 6;
  const int nw = gridDim.x * 4;
  const float bb0 = bias ? bias[lane]      : 0.f;
  const float bb1 = bias ? bias[lane + 64] : 0.f;

  for (int n = blockIdx.x * 4 + wave; n < N; n += nw){
    float f0 = h[(size_t)n * HD + lane];
    float f1 = h[(size_t)n * HD + 64 + lane];
    float f2 = (isSrc && lane < TD) ? t_emb[(size_t)n * TD + lane] : 0.f;
    float a0 = bb0, a1 = bb1;
    #pragma unroll
    for (int k = 0; k < 64; ++k){
      float fk = __shfl(f0, k);
      unsigned int w = Wp[k * 64 + lane];
      a0 = fmaf(fk, unplo(w), a0); a1 = fmaf(fk, unphi(w), a1);
    }
    #pragma unroll
    for (int k = 0; k < 64; ++k){
      float fk = __shfl(f1, k);
      unsigned int w = Wp[(64 + k) * 64 + lane];
      a0 = fmaf(fk, unplo(w), a0); a1 = fmaf(fk, unphi(w), a1);
    }
    if (isSrc){
      #pragma unroll
      for (int k = 0; k < TD; ++k){
        float fk = __shfl(f2, k);
        unsigned int w = Wp[(HD + k) * 64 + lane];
        a0 = fmaf(fk, unplo(w), a0); a1 = fmaf(fk, unphi(w), a1);
      }
    }
    out[(size_t)n * HD + lane]      = f2b(a0);
    out[(size_t)n * HD + 64 + lane] = f2b(a1);
  }
}

// ---------------------------------------------------------------------------
// Kernel 2: message path. Block = 4 waves, tile = 16 edges.
//  - 256 threads stage bf16 table sums coalesced into LDS (Ssh)
//  - tail MFMA: A=[ea|dist|0] (K=32), B=We_w1 rows 257..272,256 (regs)
//  - merge sums + silu -> u (bf16, same LDS buffer)
//  - layer-2 MFMA: wave w owns cols [32w,32w+32), B2 in regs
//  - attention dot cross-wave via LDS; m-values via LDS -> full-line atomics
// ---------------------------------------------------------------------------
__global__ void __launch_bounds__(256) k_edge_msg(
    const int* __restrict__ ei, const float* __restrict__ x,
    const float* __restrict__ ea,
    const unsigned short* __restrict__ Aes, const unsigned short* __restrict__ Aed,
    const float* __restrict__ We_w1, const float* __restrict__ We_w2,
    const float* __restrict__ We_b2, const float* __restrict__ Watt_w,
    const float* __restrict__ Watt_b,
    float* __restrict__ msg_agg, int E)
{
  __shared__ unsigned short Ssh[16 * 136];   // table sums -> u (bf16)
  __shared__ unsigned short Atl[16 * 40];    // tail A [edge][k<32]
  __shared__ float          Msh[16 * 132];   // m values (fp32)
  __shared__ float          attP[4 * 16];    // per-wave attention partials
  __shared__ int            dsh[16];

  const int tid  = threadIdx.x;
  const int lane = tid & 63, w = tid >> 6;
  const int m = lane & 15, q = lane >> 4;

  // ---- one-time register B-fragments ----
  short8 B2[4][2];
  short8 Bt[2];
  float web2[2], watt[2];
  #pragma unroll
  for (int tt = 0; tt < 2; ++tt){
    const int col = (2 * w + tt) * 16 + m;
    web2[tt] = We_b2[col];
    watt[tt] = Watt_w[col];
    #pragma unroll
    for (int step = 0; step < 4; ++step){
      union { short8 v; unsigned short u[8]; } b;
      #pragma unroll
      for (int j = 0; j < 8; ++j)
        b.u[j] = f2b(We_w2[(step * 32 + q * 8 + j) * 128 + col]);
      B2[step][tt] = b.v;
    }
    union { short8 v; unsigned short u[8]; } bt;
    #pragma unroll
    for (int j = 0; j < 8; ++j){
      int k = q * 8 + j;
      float wv = (k < 16) ? We_w1[(257 + k) * 128 + col]
               : (k == 16 ? We_w1[256 * 128 + col] : 0.f);
      bt.u[j] = f2b(wv);
    }
    Bt[tt] = bt.v;
  }
  const float attb = Watt_b[0];
  const int tiles = (E + 15) >> 4;

  for (int tile = blockIdx.x; tile < tiles; tile += gridDim.x){
    const int e0 = tile << 4;

    // ---- staging: thread t -> edge t>>4, 16B chunk t&15 (coalesced) ----
    {
      const int eg = tid >> 4, c = tid & 15;
      const int eC = (e0 + eg < E) ? (e0 + eg) : (E - 1);
      const int s = ei[eC], d = ei[E + eC];
      uint4 gs = *(const uint4*)(Aes + (size_t)s * HD + c * 8);
      uint4 gd = *(const uint4*)(Aed + (size_t)d * HD + c * 8);
      float fa[8], fb[8];
      unp8(gs, fa); unp8(gd, fb);
      union { short8 v; unsigned int u[4]; } sv;
      #pragma unroll
      for (int jj = 0; jj < 4; ++jj)
        sv.u[jj] = packbf(fa[2 * jj] + fb[2 * jj], fa[2 * jj + 1] + fb[2 * jj + 1]);
      *(short8*)(Ssh + eg * 136 + c * 8) = sv.v;

      Atl[eg * 40 + c] = f2b(ea[(size_t)eC * ED + c]);
      unsigned short t2 = 0;
      if (c == 0){
        float dx = x[s * 3 + 0] - x[d * 3 + 0];
        float dy = x[s * 3 + 1] - x[d * 3 + 1];
        float dz = x[s * 3 + 2] - x[d * 3 + 2];
        float dist = dx * dx + dy * dy + dz * dz;
        t2 = f2b(dist);
        dsh[eg] = d;
      }
      Atl[eg * 40 + 16 + c] = t2;
    }
    __syncthreads();

    // ---- tail MFMA + merge + silu ----
    {
      short8 a = *(const short8*)(Atl + m * 40 + q * 8);
      float4v t0 = {0.f, 0.f, 0.f, 0.f}, t1 = {0.f, 0.f, 0.f, 0.f};
      t0 = __builtin_amdgcn_mfma_f32_16x16x32_bf16(a, Bt[0], t0, 0, 0, 0);
      t1 = __builtin_amdgcn_mfma_f32_16x16x32_bf16(a, Bt[1], t1, 0, 0, 0);
      #pragma unroll
      for (int r = 0; r < 4; ++r){
        const int row = q * 4 + r;
        const int i0 = row * 136 + (2 * w + 0) * 16 + m;
        const int i1 = row * 136 + (2 * w + 1) * 16 + m;
        float u0 = siluf(t0[r] + b2f(Ssh[i0]));
        float u1 = siluf(t1[r] + b2f(Ssh[i1]));
        Ssh[i0] = f2b(u0);
        Ssh[i1] = f2b(u1);
      }
    }
    __syncthreads();

    // ---- layer-2 MFMA ----
    float4v c0 = {0.f, 0.f, 0.f, 0.f}, c1 = {0.f, 0.f, 0.f, 0.f};
    #pragma unroll
    for (int step = 0; step < 4; ++step){
      short8 a2 = *(const short8*)(Ssh + m * 136 + step * 32 + q * 8);
      c0 = __builtin_amdgcn_mfma_f32_16x16x32_bf16(a2, B2[step][0], c0, 0, 0, 0);
      c1 = __builtin_amdgcn_mfma_f32_16x16x32_bf16(a2, B2[step][1], c1, 0, 0, 0);
    }

    // ---- epilogue: m values + attention partials ----
    float ap[4];
    #pragma unroll
    for (int r = 0; r < 4; ++r){
      float m0 = c0[r] + web2[0];
      float m1 = c1[r] + web2[1];
      Msh[(q * 4 + r) * 132 + (2 * w + 0) * 16 + m] = m0;
      Msh[(q * 4 + r) * 132 + (2 * w + 1) * 16 + m] = m1;
      float p = fmaf(m0, watt[0], m1 * watt[1]);
      p += __shfl_xor(p, 1); p += __shfl_xor(p, 2);
      p += __shfl_xor(p, 4); p += __shfl_xor(p, 8);
      ap[r] = p;
    }
    if (m == 0){
      #pragma unroll
      for (int r = 0; r < 4; ++r) attP[w * 16 + q * 4 + r] = ap[r];
    }
    __syncthreads();

    // ---- atomic scatter: 2 passes x (8 edges x 32 cols) -> full 128B lines ----
    #pragma unroll
    for (int pass = 0; pass < 2; ++pass){
      const int eg  = (tid >> 5) + pass * 8;
      const int col = tid & 31;
      if (e0 + eg < E){
        float as  = attP[eg] + attP[16 + eg] + attP[32 + eg] + attP[48 + eg] + attb;
        float att = 1.f / (1.f + __expf(-as));
        float* base = msg_agg + (size_t)dsh[eg] * HD;
        #pragma unroll
        for (int j = 0; j < 4; ++j)
          atomAddF(base + col + 32 * j, att * Msh[eg * 132 + col + 32 * j]);
      }
    }
    __syncthreads();
  }
}

// ---------------------------------------------------------------------------
// Kernel 3: coord path. Same structure; epilogue = tanh(dot) scatter (3 comps).
// ---------------------------------------------------------------------------
__global__ void __launch_bounds__(256) k_edge_coord(
    const int* __restrict__ ei, const float* __restrict__ x,
    const float* __restrict__ ea,
    const unsigned short* __restrict__ Axs, const unsigned short* __restrict__ Axd,
    const float* __restrict__ Wx_w1, const float* __restrict__ Wx_w2,
    const float* __restrict__ Wx_b2, const float* __restrict__ Wx_w3,
    float* __restrict__ xout, int E)
{
  __shared__ unsigned short Ssh[16 * 136];
  __shared__ unsigned short Atl[16 * 40];
  __shared__ float          cwP[4 * 16];
  __shared__ float          xdsh[3 * 16];
  __shared__ float          rssh[16];
  __shared__ int            dsh[16];

  const int tid  = threadIdx.x;
  const int lane = tid & 63, w = tid >> 6;
  const int m = lane & 15, q = lane >> 4;

  short8 B2[4][2];
  short8 Bt[2];
  float wxb2[2], w3v[2];
  #pragma unroll
  for (int tt = 0; tt < 2; ++tt){
    const int col = (2 * w + tt) * 16 + m;
    wxb2[tt] = Wx_b2[col];
    w3v[tt]  = Wx_w3[col];
    #pragma unroll
    for (int step = 0; step < 4; ++step){
      union { short8 v; unsigned short u[8]; } b;
      #pragma unroll
      for (int j = 0; j < 8; ++j)
        b.u[j] = f2b(Wx_w2[(step * 32 + q * 8 + j) * 128 + col]);
      B2[step][tt] = b.v;
    }
    union { short8 v; unsigned short u[8]; } bt;
    #pragma unroll
    for (int j = 0; j < 8; ++j){
      int k = q * 8 + j;
      float wv = (k < 16) ? Wx_w1[(256 + k) * 128 + col] : 0.f;
      bt.u[j] = f2b(wv);
    }
    Bt[tt] = bt.v;
  }
  const int tiles = (E + 15) >> 4;

  for (int tile = blockIdx.x; tile < tiles; tile += gridDim.x){
    const int e0 = tile << 4;

    {
      const int eg = tid >> 4, c = tid & 15;
      const int eC = (e0 + eg < E) ? (e0 + eg) : (E - 1);
      const int s = ei[eC], d = ei[E + eC];
      uint4 gs = *(const uint4*)(Axs + (size_t)s * HD + c * 8);
      uint4 gd = *(const uint4*)(Axd + (size_t)d * HD + c * 8);
      float fa[8], fb[8];
      unp8(gs, fa); unp8(gd, fb);
      union { short8 v; unsigned int u[4]; } sv;
      #pragma unroll
      for (int jj = 0; jj < 4; ++jj)
        sv.u[jj] = packbf(fa[2 * jj] + fb[2 * jj], fa[2 * jj + 1] + fb[2 * jj + 1]);
      *(short8*)(Ssh + eg * 136 + c * 8) = sv.v;

      Atl[eg * 40 + c]      = f2b(ea[(size_t)eC * ED + c]);
      Atl[eg * 40 + 16 + c] = 0;
      if (c == 0){
        float dx = x[s * 3 + 0] - x[d * 3 + 0];
        float dy = x[s * 3 + 1] - x[d * 3 + 1];
        float dz = x[s * 3 + 2] - x[d * 3 + 2];
        float dist = dx * dx + dy * dy + dz * dz;
        xdsh[0 * 16 + eg] = dx;
        xdsh[1 * 16 + eg] = dy;
        xdsh[2 * 16 + eg] = dz;
        rssh[eg] = 2.5f / (sqrtf(dist + 1e-8f) + 1.0f);
        dsh[eg] = d;
      }
    }
    __syncthreads();

    {
      short8 a = *(const short8*)(Atl + m * 40 + q * 8);
      float4v t0 = {0.f, 0.f, 0.f, 0.f}, t1 = {0.f, 0.f, 0.f, 0.f};
      t0 = __builtin_amdgcn_mfma_f32_16x16x32_bf16(a, Bt[0], t0, 0, 0, 0);
      t1 = __builtin_amdgcn_mfma_f32_16x16x32_bf16(a, Bt[1], t1, 0, 0, 0);
      #pragma unroll
      for (int r = 0; r < 4; ++r){
        const int row = q * 4 + r;
        const int i0 = row * 136 + (2 * w + 0) * 16 + m;
        const int i1 = row * 136 + (2 * w + 1) * 16 + m;
        float u0 = siluf(t0[r] + b2f(Ssh[i0]));
        float u1 = siluf(t1[r] + b2f(Ssh[i1]));
        Ssh[i0] = f2b(u0);
        Ssh[i1] = f2b(u1);
      }
    }
    __syncthreads();

    float4v c0 = {0.f, 0.f, 0.f, 0.f}, c1 = {0.f, 0.f, 0.f, 0.f};
    #pragma unroll
    for (int step = 0; step < 4; ++step){
      short8 a2 = *(const short8*)(Ssh + m * 136 + step * 32 + q * 8);
      c0 = __builtin_amdgcn_mfma_f32_16x16x32_bf16(a2, B2[step][0], c0, 0, 0, 0);
      c1 = __builtin_amdgcn_mfma_f32_16x16x32_bf16(a2, B2[step][1], c1, 0, 0, 0);
    }

    float cp[4];
    #pragma unroll
    for (int r = 0; r < 4; ++r){
      float u0 = siluf(c0[r] + wxb2[0]);
      float u1 = siluf(c1[r] + wxb2[1]);
      float p = fmaf(u0, w3v[0], u1 * w3v[1]);
      p += __shfl_xor(p, 1); p += __shfl_xor(p, 2);
      p += __shfl_xor(p, 4); p += __shfl_xor(p, 8);
      cp[r] = p;
    }
    if (m == 0){
      #pragma unroll
      for (int r = 0; r < 4; ++r) cwP[w * 16 + q * 4 + r] = cp[r];
    }
    __syncthreads();

    if (tid < 48){
      const int eg = tid / 3, comp = tid % 3;
      if (e0 + eg < E){
        float cs = cwP[eg] + cwP[16 + eg] + cwP[32 + eg] + cwP[48 + eg];
        float sc = tanhf(cs) * rssh[eg];
        atomAddF(xout + (size_t)dsh[eg] * 3 + comp, xdsh[comp * 16 + eg] * sc);
      }
    }
    __syncthreads();
  }
}

// ---------------------------------------------------------------------------
// Kernel 4a: z = h @ Wh_w1[0:128] + Wh_b1
// ---------------------------------------------------------------------------
__global__ void __launch_bounds__(256) k_h1a(
    const float* __restrict__ h, const float* __restrict__ Wh_w1,
    const float* __restrict__ Wh_b1, float* __restrict__ z, int N)
{
  __shared__ unsigned int Wp[HD * 64];
  for (int i = threadIdx.x; i < HD * 64; i += 256){
    int k = i >> 6, l = i & 63;
    Wp[i] = packbf(Wh_w1[k * HD + l], Wh_w1[k * HD + l + 64]);
  }
  __syncthreads();

  const int lane = threadIdx.x & 63, wave = threadIdx.x >> 6;
  const int nw = gridDim.x * 4;
  const float bb0 = Wh_b1[lane], bb1 = Wh_b1[lane + 64];

  for (int n = blockIdx.x * 4 + wave; n < N; n += nw){
    float f0 = h[(size_t)n * HD + lane];
    float f1 = h[(size_t)n * HD + 64 + lane];
    float a0 = bb0, a1 = bb1;
    #pragma unroll
    for (int k = 0; k < 64; ++k){
      float fk = __shfl(f0, k);
      unsigned int w = Wp[k * 64 + lane];
      a0 = fmaf(fk, unplo(w), a0); a1 = fmaf(fk, unphi(w), a1);
    }
    #pragma unroll
    for (int k = 0; k < 64; ++k){
      float fk = __shfl(f1, k);
      unsigned int w = Wp[(64 + k) * 64 + lane];
      a0 = fmaf(fk, unplo(w), a0); a1 = fmaf(fk, unphi(w), a1);
    }
    z[(size_t)n * HD + lane]      = a0;
    z[(size_t)n * HD + 64 + lane] = a1;
  }
}

// ---------------------------------------------------------------------------
// Kernel 4b: z = silu(z + msg @ Wh_w1[128:256])
// ---------------------------------------------------------------------------
__global__ void __launch_bounds__(256) k_h1b(
    const float* __restrict__ msg, const float* __restrict__ Wh_w1,
    float* __restrict__ z, int N)
{
  __shared__ unsigned int Wp[HD * 64];
  for (int i = threadIdx.x; i < HD * 64; i += 256){
    int k = i >> 6, l = i & 63;
    Wp[i] = packbf(Wh_w1[(HD + k) * HD + l], Wh_w1[(HD + k) * HD + l + 64]);
  }
  __syncthreads();

  const int lane = threadIdx.x & 63, wave = threadIdx.x >> 6;
  const int nw = gridDim.x * 4;

  for (int n = blockIdx.x * 4 + wave; n < N; n += nw){
    float f0 = msg[(size_t)n * HD + lane];
    float f1 = msg[(size_t)n * HD + 64 + lane];
    float a0 = z[(size_t)n * HD + lane];
    float a1 = z[(size_t)n * HD + 64 + lane];
    #pragma unroll
    for (int k = 0; k < 64; ++k){
      float fk = __shfl(f0, k);
      unsigned int w = Wp[k * 64 + lane];
      a0 = fmaf(fk, unplo(w), a0); a1 = fmaf(fk, unphi(w), a1);
    }
    #pragma unroll
    for (int k = 0; k < 64; ++k){
      float fk = __shfl(f1, k);
      unsigned int w = Wp[(64 + k) * 64 + lane];
      a0 = fmaf(fk, unplo(w), a0); a1 = fmaf(fk, unphi(w), a1);
    }
    z[(size_t)n * HD + lane]      = siluf(a0);
    z[(size_t)n * HD + 64 + lane] = siluf(a1);
  }
}

// ---------------------------------------------------------------------------
// Kernel 5: hout = h + z @ Wh_w2 + Wh_b2
// ---------------------------------------------------------------------------
__global__ void __launch_bounds__(256) k_h2(
    const float* __restrict__ h, const float* __restrict__ z,
    const float* __restrict__ Wh_w2, const float* __restrict__ Wh_b2,
    float* __restrict__ hout, int N)
{
  __shared__ unsigned int Wp[HD * 64];
  for (int i = threadIdx.x; i < HD * 64; i += 256){
    int k = i >> 6, l = i & 63;
    Wp[i] = packbf(Wh_w2[k * HD + l], Wh_w2[k * HD + l + 64]);
  }
  __syncthreads();

  const int lane = threadIdx.x & 63, wave = threadIdx.x >> 6;
  const int nw = gridDim.x * 4;
  const float bb0 = Wh_b2[lane], bb1 = Wh_b2[lane + 64];

  for (int n = blockIdx.x * 4 + wave; n < N; n += nw){
    float f0 = z[(size_t)n * HD + lane];
    float f1 = z[(size_t)n * HD + 64 + lane];
    float a0 = bb0, a1 = bb1;
    #pragma unroll
    for (int k = 0; k < 64; ++k){
      float fk = __shfl(f0, k);
      unsigned int w = Wp[k * 64 + lane];
      a0 = fmaf(fk, unplo(w), a0); a1 = fmaf(fk, unphi(w), a1);
    }
    #pragma unroll
    for (int k = 0; k < 64; ++k){
      float fk = __shfl(f1, k);
      unsigned int w = Wp[(64 + k) * 64 + lane];
      a0 = fmaf(fk, unplo(w), a0); a1 = fmaf(fk, unphi(w), a1);
    }
    hout[(size_t)n * HD + lane]      = h[(size_t)n * HD + lane]      + a0;
    hout[(size_t)n * HD + 64 + lane] = h[(size_t)n * HD + 64 + lane] + a1;
  }
}

extern "C" void kernel_launch(void* const* d_in, const int* in_sizes, int n_in,
                              void* d_out, int out_size, void* d_ws, size_t ws_size,
                              hipStream_t stream)
{
  const float* h      = (const float*)d_in[0];
  const float* x      = (const float*)d_in[1];
  const int*   ei     = (const int*)  d_in[2];
  const float* ea     = (const float*)d_in[3];
  const float* t_emb  = (const float*)d_in[4];
  const float* We_w1  = (const float*)d_in[5];
  const float* We_b1  = (const float*)d_in[6];
  const float* We_w2  = (const float*)d_in[7];
  const float* We_b2  = (const float*)d_in[8];
  const float* Watt_w = (const float*)d_in[9];
  const float* Watt_b = (const float*)d_in[10];
  const float* Wx_w1  = (const float*)d_in[11];
  const float* Wx_b1  = (const float*)d_in[12];
  const float* Wx_w2  = (const float*)d_in[13];
  const float* Wx_b2  = (const float*)d_in[14];
  const float* Wx_w3  = (const float*)d_in[15];
  const float* Wh_w1  = (const float*)d_in[16];
  const float* Wh_b1  = (const float*)d_in[17];
  const float* Wh_w2  = (const float*)d_in[18];
  const float* Wh_b2  = (const float*)d_in[19];

  const int N = in_sizes[0] / HD;
  const int E = in_sizes[2] / 2;

  char* ws = (char*)d_ws;
  unsigned short* Aes = (unsigned short*)ws;  ws += (size_t)N * HD * 2;
  unsigned short* Aed = (unsigned short*)ws;  ws += (size_t)N * HD * 2;
  unsigned short* Axs = (unsigned short*)ws;  ws += (size_t)N * HD * 2;
  unsigned short* Axd = (unsigned short*)ws;  ws += (size_t)N * HD * 2;
  float* msg_agg = (float*)ws;                ws += (size_t)N * HD * 4;
  float* z       = (float*)ws;                ws += (size_t)N * HD * 4;

  float* hout = (float*)d_out;
  float* xout = hout + (size_t)N * HD;

  hipMemsetAsync(msg_agg, 0, (size_t)N * HD * 4, stream);
  hipMemcpyAsync(xout, x, (size_t)N * 3 * 4, hipMemcpyDeviceToDevice, stream);

  dim3 gP(128, 4);
  k_pre<<<gP, 256, 0, stream>>>(h, t_emb, We_w1, We_b1, Wx_w1, Wx_b1,
                                Aes, Aed, Axs, Axd, N);
  k_h1a<<<512, 256, 0, stream>>>(h, Wh_w1, Wh_b1, z, N);
  k_edge_msg<<<2048, 256, 0, stream>>>(ei, x, ea, Aes, Aed, We_w1, We_w2, We_b2,
                                       Watt_w, Watt_b, msg_agg, E);
  k_edge_coord<<<2048, 256, 0, stream>>>(ei, x, ea, Axs, Axd, Wx_w1, Wx_w2, Wx_b2,
                                         Wx_w3, xout, E);
  k_h1b<<<512, 256, 0, stream>>>(msg_agg, Wh_w1, z, N);
  k_h2<<<512, 256, 0, stream>>>(h, z, Wh_w2, Wh_b2, hout, N);
}

// Round 4
// 679.254 us; speedup vs baseline: 9.9658x; 2.6405x over previous
//
#include <hip/hip_runtime.h>
#include <hip/hip_bf16.h>

#define HD 128
#define ED 16
#define TD 32

typedef __attribute__((ext_vector_type(8))) short short8;
typedef __attribute__((ext_vector_type(4))) float float4v;

__device__ __forceinline__ float siluf(float v){ return v * (1.0f / (1.0f + __expf(-v))); }

// bf16 pack/unpack helpers (RTNE)
__device__ __forceinline__ unsigned int bfbits(float x){
  unsigned int a = __float_as_uint(x);
  return (a + 0x7fffu + ((a >> 16) & 1u)) >> 16;
}
__device__ __forceinline__ unsigned int packbf(float lo, float hi){
  return (bfbits(lo) & 0xffffu) | (bfbits(hi) << 16);
}
__device__ __forceinline__ float unplo(unsigned int w){ return __uint_as_float(w << 16); }
__device__ __forceinline__ float unphi(unsigned int w){ return __uint_as_float(w & 0xffff0000u); }
__device__ __forceinline__ float b2f(unsigned short s){ return __uint_as_float(((unsigned int)s) << 16); }
__device__ __forceinline__ unsigned short f2b(float x){ return (unsigned short)bfbits(x); }

__device__ __forceinline__ void unp8(uint4 u, float* f){
  f[0]=unplo(u.x); f[1]=unphi(u.x); f[2]=unplo(u.y); f[3]=unphi(u.y);
  f[4]=unplo(u.z); f[5]=unphi(u.z); f[6]=unplo(u.w); f[7]=unphi(u.w);
}

__device__ __forceinline__ void atomAddF(float* p, float v){
  unsafeAtomicAdd(p, v);  // HW global_atomic_add_f32 on gfx950
}

// ---------------------------------------------------------------------------
// Kernel 1: node-side first-layer GEMMs via MFMA. blockIdx.y = group:
//  0: Aes  = bf16( [h|t] @ (We_w1 rows 0..127 | 273..304) + We_b1 )
//  1: Aed  = bf16(  h    @  We_w1 rows 128..255 )
//  2: Axs  = bf16( [h|t] @ (Wx_w1 rows 0..127 | 272..303) + Wx_b1 )
//  3: Axd  = bf16(  h    @  Wx_w1 rows 128..255 )
//  4: zpre = bf16(  h    @  Wh_w1 rows 0..127   + Wh_b1 )
// A-frags loaded directly from global (consecutive node rows -> full sectors).
// ---------------------------------------------------------------------------
__global__ void __launch_bounds__(256) k_pre2(
    const float* __restrict__ h, const float* __restrict__ t_emb,
    const float* __restrict__ We_w1, const float* __restrict__ We_b1,
    const float* __restrict__ Wx_w1, const float* __restrict__ Wx_b1,
    const float* __restrict__ Wh_w1, const float* __restrict__ Wh_b1,
    unsigned short* __restrict__ Aes, unsigned short* __restrict__ Aed,
    unsigned short* __restrict__ Axs, unsigned short* __restrict__ Axd,
    unsigned short* __restrict__ zpre, int N)
{
  __shared__ unsigned short Wt[128 * 168];   // [col][k], 43008 B
  __shared__ unsigned short OutS[64 * 136];  // [node][col], 17408 B

  const int group = blockIdx.y;
  const float* Wsrc = (group <= 1) ? We_w1 : (group <= 3) ? Wx_w1 : Wh_w1;
  const float* bias = (group == 0) ? We_b1 : (group == 2) ? Wx_b1
                    : (group == 4) ? Wh_b1 : nullptr;
  unsigned short* out = (group == 0) ? Aes : (group == 1) ? Aed
                      : (group == 2) ? Axs : (group == 3) ? Axd : zpre;
  const int rowBase = (group == 1 || group == 3) ? 128 : 0;
  const int tBase   = (group == 0) ? 273 : (group == 2) ? 272 : -1;

  for (int i = threadIdx.x; i < 160 * 128; i += 256){
    int k = i >> 7, col = i & 127;
    float wv = 0.f;
    if (k < 128)      wv = Wsrc[(rowBase + k) * 128 + col];
    else if (tBase >= 0) wv = Wsrc[(tBase + (k - 128)) * 128 + col];
    Wt[col * 168 + k] = f2b(wv);
  }
  __syncthreads();

  const int lane = threadIdx.x & 63, w = threadIdx.x >> 6;
  const int m = lane & 15, q = lane >> 4;
  float bb[8];
  #pragma unroll
  for (int t = 0; t < 8; ++t) bb[t] = bias ? bias[t * 16 + m] : 0.f;

  const int ntiles = (N + 63) >> 6;
  for (int tile = blockIdx.x; tile < ntiles; tile += gridDim.x){
    const int n0 = tile << 6;
    const int n = min(n0 + w * 16 + m, N - 1);

    short8 a[5];
    #pragma unroll
    for (int step = 0; step < 4; ++step){
      float4 v0 = *(const float4*)(h + (size_t)n * 128 + step * 32 + q * 8);
      float4 v1 = *(const float4*)(h + (size_t)n * 128 + step * 32 + q * 8 + 4);
      union { short8 s; unsigned int u[4]; } av;
      av.u[0] = packbf(v0.x, v0.y); av.u[1] = packbf(v0.z, v0.w);
      av.u[2] = packbf(v1.x, v1.y); av.u[3] = packbf(v1.z, v1.w);
      a[step] = av.s;
    }
    {
      float4 v0 = *(const float4*)(t_emb + (size_t)n * 32 + q * 8);
      float4 v1 = *(const float4*)(t_emb + (size_t)n * 32 + q * 8 + 4);
      union { short8 s; unsigned int u[4]; } av;
      av.u[0] = packbf(v0.x, v0.y); av.u[1] = packbf(v0.z, v0.w);
      av.u[2] = packbf(v1.x, v1.y); av.u[3] = packbf(v1.z, v1.w);
      a[4] = av.s;
    }

    float4v acc[8];
    #pragma unroll
    for (int t = 0; t < 8; ++t) acc[t] = (float4v){0.f, 0.f, 0.f, 0.f};
    #pragma unroll
    for (int step = 0; step < 5; ++step){
      #pragma unroll
      for (int t = 0; t < 8; ++t){
        short8 b = *(const short8*)(Wt + (size_t)(t * 16 + m) * 168 + step * 32 + q * 8);
        acc[t] = __builtin_amdgcn_mfma_f32_16x16x32_bf16(a[step], b, acc[t], 0, 0, 0);
      }
    }

    // stage D -> LDS (bf16), then coalesced 16B stores
    #pragma unroll
    for (int t = 0; t < 8; ++t)
      #pragma unroll
      for (int r = 0; r < 4; ++r)
        OutS[(w * 16 + q * 4 + r) * 136 + t * 16 + m] = f2b(acc[t][r] + bb[t]);
    __syncthreads();
    for (int i = threadIdx.x; i < 64 * 16; i += 256){
      int node = i >> 4, seg = i & 15;
      int nn = n0 + node;
      if (nn < N)
        *(uint4*)(out + (size_t)nn * 128 + seg * 8) =
            *(const uint4*)(OutS + node * 136 + seg * 8);
    }
    __syncthreads();
  }
}

// ---------------------------------------------------------------------------
// Kernel 2: message path. Block = 4 waves, tile = 16 edges. (unchanged R3)
// ---------------------------------------------------------------------------
__global__ void __launch_bounds__(256) k_edge_msg(
    const int* __restrict__ ei, const float* __restrict__ x,
    const float* __restrict__ ea,
    const unsigned short* __restrict__ Aes, const unsigned short* __restrict__ Aed,
    const float* __restrict__ We_w1, const float* __restrict__ We_w2,
    const float* __restrict__ We_b2, const float* __restrict__ Watt_w,
    const float* __restrict__ Watt_b,
    float* __restrict__ msg_agg, int E)
{
  __shared__ unsigned short Ssh[16 * 136];
  __shared__ unsigned short Atl[16 * 40];
  __shared__ float          Msh[16 * 132];
  __shared__ float          attP[4 * 16];
  __shared__ int            dsh[16];

  const int tid  = threadIdx.x;
  const int lane = tid & 63, w = tid >> 6;
  const int m = lane & 15, q = lane >> 4;

  short8 B2[4][2];
  short8 Bt[2];
  float web2[2], watt[2];
  #pragma unroll
  for (int tt = 0; tt < 2; ++tt){
    const int col = (2 * w + tt) * 16 + m;
    web2[tt] = We_b2[col];
    watt[tt] = Watt_w[col];
    #pragma unroll
    for (int step = 0; step < 4; ++step){
      union { short8 v; unsigned short u[8]; } b;
      #pragma unroll
      for (int j = 0; j < 8; ++j)
        b.u[j] = f2b(We_w2[(step * 32 + q * 8 + j) * 128 + col]);
      B2[step][tt] = b.v;
    }
    union { short8 v; unsigned short u[8]; } bt;
    #pragma unroll
    for (int j = 0; j < 8; ++j){
      int k = q * 8 + j;
      float wv = (k < 16) ? We_w1[(257 + k) * 128 + col]
               : (k == 16 ? We_w1[256 * 128 + col] : 0.f);
      bt.u[j] = f2b(wv);
    }
    Bt[tt] = bt.v;
  }
  const float attb = Watt_b[0];
  const int tiles = (E + 15) >> 4;

  for (int tile = blockIdx.x; tile < tiles; tile += gridDim.x){
    const int e0 = tile << 4;

    {
      const int eg = tid >> 4, c = tid & 15;
      const int eC = (e0 + eg < E) ? (e0 + eg) : (E - 1);
      const int s = ei[eC], d = ei[E + eC];
      uint4 gs = *(const uint4*)(Aes + (size_t)s * HD + c * 8);
      uint4 gd = *(const uint4*)(Aed + (size_t)d * HD + c * 8);
      float fa[8], fb[8];
      unp8(gs, fa); unp8(gd, fb);
      union { short8 v; unsigned int u[4]; } sv;
      #pragma unroll
      for (int jj = 0; jj < 4; ++jj)
        sv.u[jj] = packbf(fa[2 * jj] + fb[2 * jj], fa[2 * jj + 1] + fb[2 * jj + 1]);
      *(short8*)(Ssh + eg * 136 + c * 8) = sv.v;

      Atl[eg * 40 + c] = f2b(ea[(size_t)eC * ED + c]);
      unsigned short t2 = 0;
      if (c == 0){
        float dx = x[s * 3 + 0] - x[d * 3 + 0];
        float dy = x[s * 3 + 1] - x[d * 3 + 1];
        float dz = x[s * 3 + 2] - x[d * 3 + 2];
        float dist = dx * dx + dy * dy + dz * dz;
        t2 = f2b(dist);
        dsh[eg] = d;
      }
      Atl[eg * 40 + 16 + c] = t2;
    }
    __syncthreads();

    {
      short8 a = *(const short8*)(Atl + m * 40 + q * 8);
      float4v t0 = {0.f, 0.f, 0.f, 0.f}, t1 = {0.f, 0.f, 0.f, 0.f};
      t0 = __builtin_amdgcn_mfma_f32_16x16x32_bf16(a, Bt[0], t0, 0, 0, 0);
      t1 = __builtin_amdgcn_mfma_f32_16x16x32_bf16(a, Bt[1], t1, 0, 0, 0);
      #pragma unroll
      for (int r = 0; r < 4; ++r){
        const int row = q * 4 + r;
        const int i0 = row * 136 + (2 * w + 0) * 16 + m;
        const int i1 = row * 136 + (2 * w + 1) * 16 + m;
        float u0 = siluf(t0[r] + b2f(Ssh[i0]));
        float u1 = siluf(t1[r] + b2f(Ssh[i1]));
        Ssh[i0] = f2b(u0);
        Ssh[i1] = f2b(u1);
      }
    }
    __syncthreads();

    float4v c0 = {0.f, 0.f, 0.f, 0.f}, c1 = {0.f, 0.f, 0.f, 0.f};
    #pragma unroll
    for (int step = 0; step < 4; ++step){
      short8 a2 = *(const short8*)(Ssh + m * 136 + step * 32 + q * 8);
      c0 = __builtin_amdgcn_mfma_f32_16x16x32_bf16(a2, B2[step][0], c0, 0, 0, 0);
      c1 = __builtin_amdgcn_mfma_f32_16x16x32_bf16(a2, B2[step][1], c1, 0, 0, 0);
    }

    float ap[4];
    #pragma unroll
    for (int r = 0; r < 4; ++r){
      float m0 = c0[r] + web2[0];
      float m1 = c1[r] + web2[1];
      Msh[(q * 4 + r) * 132 + (2 * w + 0) * 16 + m] = m0;
      Msh[(q * 4 + r) * 132 + (2 * w + 1) * 16 + m] = m1;
      float p = fmaf(m0, watt[0], m1 * watt[1]);
      p += __shfl_xor(p, 1); p += __shfl_xor(p, 2);
      p += __shfl_xor(p, 4); p += __shfl_xor(p, 8);
      ap[r] = p;
    }
    if (m == 0){
      #pragma unroll
      for (int r = 0; r < 4; ++r) attP[w * 16 + q * 4 + r] = ap[r];
    }
    __syncthreads();

    #pragma unroll
    for (int pass = 0; pass < 2; ++pass){
      const int eg  = (tid >> 5) + pass * 8;
      const int col = tid & 31;
      if (e0 + eg < E){
        float as  = attP[eg] + attP[16 + eg] + attP[32 + eg] + attP[48 + eg] + attb;
        float att = 1.f / (1.f + __expf(-as));
        float* base = msg_agg + (size_t)dsh[eg] * HD;
        #pragma unroll
        for (int j = 0; j < 4; ++j)
          atomAddF(base + col + 32 * j, att * Msh[eg * 132 + col + 32 * j]);
      }
    }
    __syncthreads();
  }
}

// ---------------------------------------------------------------------------
// Kernel 3: coord path. (unchanged R3)
// ---------------------------------------------------------------------------
__global__ void __launch_bounds__(256) k_edge_coord(
    const int* __restrict__ ei, const float* __restrict__ x,
    const float* __restrict__ ea,
    const unsigned short* __restrict__ Axs, const unsigned short* __restrict__ Axd,
    const float* __restrict__ Wx_w1, const float* __restrict__ Wx_w2,
    const float* __restrict__ Wx_b2, const float* __restrict__ Wx_w3,
    float* __restrict__ xout, int E)
{
  __shared__ unsigned short Ssh[16 * 136];
  __shared__ unsigned short Atl[16 * 40];
  __shared__ float          cwP[4 * 16];
  __shared__ float          xdsh[3 * 16];
  __shared__ float          rssh[16];
  __shared__ int            dsh[16];

  const int tid  = threadIdx.x;
  const int lane = tid & 63, w = tid >> 6;
  const int m = lane & 15, q = lane >> 4;

  short8 B2[4][2];
  short8 Bt[2];
  float wxb2[2], w3v[2];
  #pragma unroll
  for (int tt = 0; tt < 2; ++tt){
    const int col = (2 * w + tt) * 16 + m;
    wxb2[tt] = Wx_b2[col];
    w3v[tt]  = Wx_w3[col];
    #pragma unroll
    for (int step = 0; step < 4; ++step){
      union { short8 v; unsigned short u[8]; } b;
      #pragma unroll
      for (int j = 0; j < 8; ++j)
        b.u[j] = f2b(Wx_w2[(step * 32 + q * 8 + j) * 128 + col]);
      B2[step][tt] = b.v;
    }
    union { short8 v; unsigned short u[8]; } bt;
    #pragma unroll
    for (int j = 0; j < 8; ++j){
      int k = q * 8 + j;
      float wv = (k < 16) ? Wx_w1[(256 + k) * 128 + col] : 0.f;
      bt.u[j] = f2b(wv);
    }
    Bt[tt] = bt.v;
  }
  const int tiles = (E + 15) >> 4;

  for (int tile = blockIdx.x; tile < tiles; tile += gridDim.x){
    const int e0 = tile << 4;

    {
      const int eg = tid >> 4, c = tid & 15;
      const int eC = (e0 + eg < E) ? (e0 + eg) : (E - 1);
      const int s = ei[eC], d = ei[E + eC];
      uint4 gs = *(const uint4*)(Axs + (size_t)s * HD + c * 8);
      uint4 gd = *(const uint4*)(Axd + (size_t)d * HD + c * 8);
      float fa[8], fb[8];
      unp8(gs, fa); unp8(gd, fb);
      union { short8 v; unsigned int u[4]; } sv;
      #pragma unroll
      for (int jj = 0; jj < 4; ++jj)
        sv.u[jj] = packbf(fa[2 * jj] + fb[2 * jj], fa[2 * jj + 1] + fb[2 * jj + 1]);
      *(short8*)(Ssh + eg * 136 + c * 8) = sv.v;

      Atl[eg * 40 + c]      = f2b(ea[(size_t)eC * ED + c]);
      Atl[eg * 40 + 16 + c] = 0;
      if (c == 0){
        float dx = x[s * 3 + 0] - x[d * 3 + 0];
        float dy = x[s * 3 + 1] - x[d * 3 + 1];
        float dz = x[s * 3 + 2] - x[d * 3 + 2];
        float dist = dx * dx + dy * dy + dz * dz;
        xdsh[0 * 16 + eg] = dx;
        xdsh[1 * 16 + eg] = dy;
        xdsh[2 * 16 + eg] = dz;
        rssh[eg] = 2.5f / (sqrtf(dist + 1e-8f) + 1.0f);
        dsh[eg] = d;
      }
    }
    __syncthreads();

    {
      short8 a = *(const short8*)(Atl + m * 40 + q * 8);
      float4v t0 = {0.f, 0.f, 0.f, 0.f}, t1 = {0.f, 0.f, 0.f, 0.f};
      t0 = __builtin_amdgcn_mfma_f32_16x16x32_bf16(a, Bt[0], t0, 0, 0, 0);
      t1 = __builtin_amdgcn_mfma_f32_16x16x32_bf16(a, Bt[1], t1, 0, 0, 0);
      #pragma unroll
      for (int r = 0; r < 4; ++r){
        const int row = q * 4 + r;
        const int i0 = row * 136 + (2 * w + 0) * 16 + m;
        const int i1 = row * 136 + (2 * w + 1) * 16 + m;
        float u0 = siluf(t0[r] + b2f(Ssh[i0]));
        float u1 = siluf(t1[r] + b2f(Ssh[i1]));
        Ssh[i0] = f2b(u0);
        Ssh[i1] = f2b(u1);
      }
    }
    __syncthreads();

    float4v c0 = {0.f, 0.f, 0.f, 0.f}, c1 = {0.f, 0.f, 0.f, 0.f};
    #pragma unroll
    for (int step = 0; step < 4; ++step){
      short8 a2 = *(const short8*)(Ssh + m * 136 + step * 32 + q * 8);
      c0 = __builtin_amdgcn_mfma_f32_16x16x32_bf16(a2, B2[step][0], c0, 0, 0, 0);
      c1 = __builtin_amdgcn_mfma_f32_16x16x32_bf16(a2, B2[step][1], c1, 0, 0, 0);
    }

    float cp[4];
    #pragma unroll
    for (int r = 0; r < 4; ++r){
      float u0 = siluf(c0[r] + wxb2[0]);
      float u1 = siluf(c1[r] + wxb2[1]);
      float p = fmaf(u0, w3v[0], u1 * w3v[1]);
      p += __shfl_xor(p, 1); p += __shfl_xor(p, 2);
      p += __shfl_xor(p, 4); p += __shfl_xor(p, 8);
      cp[r] = p;
    }
    if (m == 0){
      #pragma unroll
      for (int r = 0; r < 4; ++r) cwP[w * 16 + q * 4 + r] = cp[r];
    }
    __syncthreads();

    if (tid < 48){
      const int eg = tid / 3, comp = tid % 3;
      if (e0 + eg < E){
        float cs = cwP[eg] + cwP[16 + eg] + cwP[32 + eg] + cwP[48 + eg];
        float sc = tanhf(cs) * rssh[eg];
        atomAddF(xout + (size_t)dsh[eg] * 3 + comp, xdsh[comp * 16 + eg] * sc);
      }
    }
    __syncthreads();
  }
}

// ---------------------------------------------------------------------------
// Kernel 4: z2 = bf16( silu( zpre + msg @ Wh_w1[128:256] ) )  (MFMA)
// ---------------------------------------------------------------------------
__global__ void __launch_bounds__(256) k_h1b2(
    const float* __restrict__ msg, const unsigned short* __restrict__ zpre,
    const float* __restrict__ Wh_w1, unsigned short* __restrict__ z2, int N)
{
  __shared__ unsigned short Wt[128 * 136];   // [col][k], 34816 B
  __shared__ unsigned short OutS[64 * 136];  // 17408 B

  for (int i = threadIdx.x; i < 128 * 128; i += 256){
    int k = i >> 7, col = i & 127;
    Wt[col * 136 + k] = f2b(Wh_w1[(128 + k) * 128 + col]);
  }
  __syncthreads();

  const int lane = threadIdx.x & 63, w = threadIdx.x >> 6;
  const int m = lane & 15, q = lane >> 4;

  const int ntiles = (N + 63) >> 6;
  for (int tile = blockIdx.x; tile < ntiles; tile += gridDim.x){
    const int n0 = tile << 6;
    const int n = min(n0 + w * 16 + m, N - 1);

    short8 a[4];
    #pragma unroll
    for (int step = 0; step < 4; ++step){
      float4 v0 = *(const float4*)(msg + (size_t)n * 128 + step * 32 + q * 8);
      float4 v1 = *(const float4*)(msg + (size_t)n * 128 + step * 32 + q * 8 + 4);
      union { short8 s; unsigned int u[4]; } av;
      av.u[0] = packbf(v0.x, v0.y); av.u[1] = packbf(v0.z, v0.w);
      av.u[2] = packbf(v1.x, v1.y); av.u[3] = packbf(v1.z, v1.w);
      a[step] = av.s;
    }

    float4v acc[8];
    #pragma unroll
    for (int t = 0; t < 8; ++t) acc[t] = (float4v){0.f, 0.f, 0.f, 0.f};
    #pragma unroll
    for (int step = 0; step < 4; ++step){
      #pragma unroll
      for (int t = 0; t < 8; ++t){
        short8 b = *(const short8*)(Wt + (size_t)(t * 16 + m) * 136 + step * 32 + q * 8);
        acc[t] = __builtin_amdgcn_mfma_f32_16x16x32_bf16(a[step], b, acc[t], 0, 0, 0);
      }
    }

    #pragma unroll
    for (int t = 0; t < 8; ++t)
      #pragma unroll
      for (int r = 0; r < 4; ++r)
        OutS[(w * 16 + q * 4 + r) * 136 + t * 16 + m] = f2b(acc[t][r]);
    __syncthreads();
    for (int i = threadIdx.x; i < 64 * 16; i += 256){
      int node = i >> 4, seg = i & 15;
      int nn = n0 + node;
      if (nn < N){
        uint4 dv = *(const uint4*)(OutS + node * 136 + seg * 8);
        uint4 zv = *(const uint4*)(zpre + (size_t)nn * 128 + seg * 8);
        float fd[8], fz[8];
        unp8(dv, fd); unp8(zv, fz);
        uint4 ov;
        ov.x = packbf(siluf(fz[0] + fd[0]), siluf(fz[1] + fd[1]));
        ov.y = packbf(siluf(fz[2] + fd[2]), siluf(fz[3] + fd[3]));
        ov.z = packbf(siluf(fz[4] + fd[4]), siluf(fz[5] + fd[5]));
        ov.w = packbf(siluf(fz[6] + fd[6]), siluf(fz[7] + fd[7]));
        *(uint4*)(z2 + (size_t)nn * 128 + seg * 8) = ov;
      }
    }
    __syncthreads();
  }
}

// ---------------------------------------------------------------------------
// Kernel 5: hout = h + z2 @ Wh_w2 + Wh_b2  (MFMA, fp32 out)
// ---------------------------------------------------------------------------
__global__ void __launch_bounds__(256) k_h22(
    const float* __restrict__ h, const unsigned short* __restrict__ z2,
    const float* __restrict__ Wh_w2, const float* __restrict__ Wh_b2,
    float* __restrict__ hout, int N)
{
  __shared__ unsigned short Wt[128 * 136];   // 34816 B
  __shared__ float OutSf[64 * 132];          // 33792 B

  for (int i = threadIdx.x; i < 128 * 128; i += 256){
    int k = i >> 7, col = i & 127;
    Wt[col * 136 + k] = f2b(Wh_w2[k * 128 + col]);
  }
  __syncthreads();

  const int lane = threadIdx.x & 63, w = threadIdx.x >> 6;
  const int m = lane & 15, q = lane >> 4;
  float bb[8];
  #pragma unroll
  for (int t = 0; t < 8; ++t) bb[t] = Wh_b2[t * 16 + m];

  const int ntiles = (N + 63) >> 6;
  for (int tile = blockIdx.x; tile < ntiles; tile += gridDim.x){
    const int n0 = tile << 6;
    const int n = min(n0 + w * 16 + m, N - 1);

    short8 a[4];
    #pragma unroll
    for (int step = 0; step < 4; ++step)
      a[step] = *(const short8*)(z2 + (size_t)n * 128 + step * 32 + q * 8);

    float4v acc[8];
    #pragma unroll
    for (int t = 0; t < 8; ++t) acc[t] = (float4v){0.f, 0.f, 0.f, 0.f};
    #pragma unroll
    for (int step = 0; step < 4; ++step){
      #pragma unroll
      for (int t = 0; t < 8; ++t){
        short8 b = *(const short8*)(Wt + (size_t)(t * 16 + m) * 136 + step * 32 + q * 8);
        acc[t] = __builtin_amdgcn_mfma_f32_16x16x32_bf16(a[step], b, acc[t], 0, 0, 0);
      }
    }

    #pragma unroll
    for (int t = 0; t < 8; ++t)
      #pragma unroll
      for (int r = 0; r < 4; ++r)
        OutSf[(w * 16 + q * 4 + r) * 132 + t * 16 + m] = acc[t][r] + bb[t];
    __syncthreads();
    for (int i = threadIdx.x; i < 64 * 32; i += 256){
      int node = i >> 5, seg = i & 31;
      int nn = n0 + node;
      if (nn < N){
        float4 dv = *(const float4*)(OutSf + node * 132 + seg * 4);
        float4 hv = *(const float4*)(h + (size_t)nn * 128 + seg * 4);
        float4 ov = {hv.x + dv.x, hv.y + dv.y, hv.z + dv.z, hv.w + dv.w};
        *(float4*)(hout + (size_t)nn * 128 + seg * 4) = ov;
      }
    }
    __syncthreads();
  }
}

extern "C" void kernel_launch(void* const* d_in, const int* in_sizes, int n_in,
                              void* d_out, int out_size, void* d_ws, size_t ws_size,
                              hipStream_t stream)
{
  const float* h      = (const float*)d_in[0];
  const float* x      = (const float*)d_in[1];
  const int*   ei     = (const int*)  d_in[2];
  const float* ea     = (const float*)d_in[3];
  const float* t_emb  = (const float*)d_in[4];
  const float* We_w1  = (const float*)d_in[5];
  const float* We_b1  = (const float*)d_in[6];
  const float* We_w2  = (const float*)d_in[7];
  const float* We_b2  = (const float*)d_in[8];
  const float* Watt_w = (const float*)d_in[9];
  const float* Watt_b = (const float*)d_in[10];
  const float* Wx_w1  = (const float*)d_in[11];
  const float* Wx_b1  = (const float*)d_in[12];
  const float* Wx_w2  = (const float*)d_in[13];
  const float* Wx_b2  = (const float*)d_in[14];
  const float* Wx_w3  = (const float*)d_in[15];
  const float* Wh_w1  = (const float*)d_in[16];
  const float* Wh_b1  = (const float*)d_in[17];
  const float* Wh_w2  = (const float*)d_in[18];
  const float* Wh_b2  = (const float*)d_in[19];

  const int N = in_sizes[0] / HD;
  const int E = in_sizes[2] / 2;

  char* ws = (char*)d_ws;
  unsigned short* Aes  = (unsigned short*)ws;  ws += (size_t)N * HD * 2;
  unsigned short* Aed  = (unsigned short*)ws;  ws += (size_t)N * HD * 2;
  unsigned short* Axs  = (unsigned short*)ws;  ws += (size_t)N * HD * 2;
  unsigned short* Axd  = (unsigned short*)ws;  ws += (size_t)N * HD * 2;
  unsigned short* zpre = (unsigned short*)ws;  ws += (size_t)N * HD * 2;
  unsigned short* z2   = (unsigned short*)ws;  ws += (size_t)N * HD * 2;
  float* msg_agg = (float*)ws;                 ws += (size_t)N * HD * 4;

  float* hout = (float*)d_out;
  float* xout = hout + (size_t)N * HD;

  hipMemsetAsync(msg_agg, 0, (size_t)N * HD * 4, stream);
  hipMemcpyAsync(xout, x, (size_t)N * 3 * 4, hipMemcpyDeviceToDevice, stream);

  dim3 gP(192, 5);
  k_pre2<<<gP, 256, 0, stream>>>(h, t_emb, We_w1, We_b1, Wx_w1, Wx_b1,
                                 Wh_w1, Wh_b1, Aes, Aed, Axs, Axd, zpre, N);
  k_edge_msg<<<2048, 256, 0, stream>>>(ei, x, ea, Aes, Aed, We_w1, We_w2, We_b2,
                                       Watt_w, Watt_b, msg_agg, E);
  k_edge_coord<<<2048, 256, 0, stream>>>(ei, x, ea, Axs, Axd, Wx_w1, Wx_w2, Wx_b2,
                                         Wx_w3, xout, E);
  k_h1b2<<<512, 256, 0, stream>>>(msg_agg, zpre, Wh_w1, z2, N);
  k_h22<<<512, 256, 0, stream>>>(h, z2, Wh_w2, Wh_b2, hout, N);
}